// Round 18
// baseline (605.614 us; speedup 1.0000x reference)
//
#include <hip/hip_runtime.h>
#include <hip/hip_cooperative_groups.h>

namespace cg = cooperative_groups;

#define EPSBN 1e-5f
#define L2E 1.44269504088896340736f

typedef __attribute__((ext_vector_type(4)))  float f32x4;
typedef __attribute__((ext_vector_type(16))) float f32x16;
typedef __attribute__((ext_vector_type(8)))  short bf16x8;

__device__ __forceinline__ unsigned short f2bf(float f) {
    unsigned u = __float_as_uint(f);
    u = (u + 0x7FFFu + ((u >> 16) & 1u)) >> 16;
    return (unsigned short)u;
}
__device__ __forceinline__ float bf2f(unsigned short h) {
    return __uint_as_float((unsigned)h << 16);
}
__device__ __forceinline__ unsigned cvt_pk_bf16(float lo, float hi) {
    unsigned r;
    asm("v_cvt_pk_bf16_f32 %0, %1, %2" : "=v"(r) : "v"(lo), "v"(hi));
    return r;
}

struct Params {
    const float* x;
    const float* w1; const float* w2;
    const float *f_w, *f_b, *f_bw, *f_bb, *f_bm, *f_bv;
    const float *g_w, *g_b, *g_bw, *g_bb, *g_bm, *g_bv;
    const float *h_w, *h_b, *h_bw, *h_bb, *h_bm, *h_bv;
    const float* gamma;
    const float *i_w, *i_b, *i_bw, *i_bb, *i_bm, *i_bv;
    float* out1;
    unsigned short* xT;
    unsigned short* fbuf;
    unsigned short* gbuf;
    float* hbuf;
    unsigned short* hT;
    unsigned short* wt1;
    unsigned short* wt2;
    unsigned short* out2T;
    float* out;
};

// ---------------------------------------------------------------------------
// Phase 0 prep: bid<256: x -> xT bf16 pixel-major; bid 256..291: weights.
// ---------------------------------------------------------------------------
__device__ __forceinline__ void prep_phase(const Params& P, char* smem,
                                           int bid, int tid)
{
    if (bid < 256) {
        unsigned short (*tls)[72] = (unsigned short (*)[72])smem;
        const int b = bid >> 6, p0 = (bid & 63) << 6;
        const int ci = tid >> 2, pq = tid & 3;
        const float* src = P.x + (((size_t)(b * 64 + ci)) << 12) + p0 + pq * 16;
#pragma unroll
        for (int j = 0; j < 4; ++j) {
            const float4 v = *(const float4*)(src + j * 4);
            const int pl = pq * 16 + j * 4;
            tls[pl][ci]     = f2bf(v.x);
            tls[pl + 1][ci] = f2bf(v.y);
            tls[pl + 2][ci] = f2bf(v.z);
            tls[pl + 3][ci] = f2bf(v.w);
        }
        __syncthreads();
        const int pix = tid >> 2, cgi = tid & 3;
        const uint4 a  = *(const uint4*)&tls[pix][cgi << 4];
        const uint4 b2 = *(const uint4*)&tls[pix][(cgi << 4) + 8];
        unsigned short* dst = P.xT + (((size_t)((b << 12) + p0 + pix)) << 6) + (cgi << 4);
        *(uint4*)dst       = a;
        *(uint4*)(dst + 8) = b2;
    } else if (bid < 292) {
        const int e0 = (bid - 256) * 2048 + tid * 8;
#pragma unroll
        for (int j = 0; j < 8; ++j) {
            const int e = e0 + j;
            const int which = e >= 36864;
            const int je = which ? e - 36864 : e;
            const int t_ = je >> 12, co = (je >> 6) & 63, ci = je & 63;
            const float val = (which ? P.w2 : P.w1)[(co * 64 + ci) * 9 + t_];
            (which ? P.wt2 : P.wt1)[je] = f2bf(val);
        }
    }
}

// ---------------------------------------------------------------------------
// Conv phase: 3x3 conv via bf16 MFMA. bid -> (r0=bid&63, cg=(bid>>6)&1,
// b=bid>>7). Needs 78,688 B LDS arena.
// ---------------------------------------------------------------------------
__device__ __forceinline__ void conv_phase(
    const unsigned short* __restrict__ xT, const unsigned short* __restrict__ wt,
    float* __restrict__ y, char* smem, int bid, int tid)
{
    unsigned short (*xs)[66][72] = (unsigned short (*)[66][72])smem;
    unsigned short (*ws)[32][72] = (unsigned short (*)[32][72])(smem + 28512);
    float (*ls)[68] = (float (*)[68])(smem + 69984);

    const int r0 = bid & 63;
    const int cgp = (bid >> 6) & 1;
    const int b = bid >> 7;

    for (int u = tid; u < 1536; u += 256) {
        const int kh = u >> 9, rem = u & 511;
        const int p = 1 + (rem >> 3), cig = rem & 7;
        const int gr = r0 + kh - 1;
        uint4 v = make_uint4(0u, 0u, 0u, 0u);
        if ((unsigned)gr < 64u)
            v = *(const uint4*)(xT + (((size_t)((b << 12) + (gr << 6) + (p - 1))) << 6) + (cig << 3));
        const int s = (p >> 3) & 7;
        *(uint4*)&xs[kh][p][(cig ^ s) << 3] = v;
    }
    if (tid < 48) {
        const int kh = tid >> 4, pp = (tid & 8) ? 65 : 0, cig = tid & 7;
        *(uint4*)&xs[kh][pp][cig << 3] = make_uint4(0u, 0u, 0u, 0u);
    }
    for (int u = tid; u < 2304; u += 256) {
        const int t_ = u >> 8, rem = u & 255;
        const int co = rem >> 3, cig = rem & 7;
        const uint4 v = *(const uint4*)(wt + (((t_ * 64) + (cgp << 5) + co) << 6) + (cig << 3));
        *(uint4*)&ws[t_][co][cig << 3] = v;
    }
    __syncthreads();

    const int lane = tid & 63, grp = tid >> 6;
    const int lr = lane & 15, lk = lane >> 4;
    const int pixbase = (grp << 4) + lr;

    f32x4 acc0 = {0.f, 0.f, 0.f, 0.f};
    f32x4 acc1 = {0.f, 0.f, 0.f, 0.f};

#pragma unroll
    for (int t = 0; t < 9; ++t) {
        const int kh = t / 3, kw = t % 3;
        const int p  = pixbase + kw;
        const int sw = ((p >> 3) & 7) << 3;
#pragma unroll
        for (int ch = 0; ch < 2; ++ch) {
            const int cio = (ch << 5) + (lk << 3);
            const bf16x8 a  = *(const bf16x8*)&xs[kh][p][cio ^ sw];
            const bf16x8 b0 = *(const bf16x8*)&ws[t][lr][cio];
            const bf16x8 b1 = *(const bf16x8*)&ws[t][16 + lr][cio];
            acc0 = __builtin_amdgcn_mfma_f32_16x16x32_bf16(a, b0, acc0, 0, 0, 0);
            acc1 = __builtin_amdgcn_mfma_f32_16x16x32_bf16(a, b1, acc1, 0, 0, 0);
        }
    }

#pragma unroll
    for (int j = 0; j < 4; ++j) {
        const int pix = (grp << 4) + (lk << 2) + j;
        ls[lr][pix]      = acc0[j];
        ls[lr + 16][pix] = acc1[j];
    }
    __syncthreads();

    const int co_l = tid >> 3, pq = (tid & 7) << 3;
    float* yp = y + (((size_t)((b << 6) + (cgp << 5) + co_l)) << 12) + (r0 << 6) + pq;
    *(float4*)yp       = *(const float4*)&ls[co_l][pq];
    *(float4*)(yp + 4) = *(const float4*)&ls[co_l][pq + 4];
}

// ---------------------------------------------------------------------------
// Proj phase (bid < 256): 4 threads/pixel x 16 ci, LDS combine. R13 numerics.
// Needs 19,200 B LDS arena.
// ---------------------------------------------------------------------------
__device__ __forceinline__ void proj_phase(const Params& P, char* smem,
                                           int bid, int tid)
{
    float (*comb)[64][25] = (float (*)[64][25])smem;

    const int pl = tid >> 2, q = tid & 3;
    const int pix = bid * 64 + pl;
    const int b = pix >> 12, p = pix & 4095;
    const int cibase = q << 4;

    const float* xp = P.out1 + ((size_t)b << 18) + ((size_t)cibase << 12) + p;

    float aF[8], aG[8], aH[8];
#pragma unroll
    for (int c = 0; c < 8; ++c) { aF[c] = 0.f; aG[c] = 0.f; aH[c] = 0.f; }

#pragma unroll
    for (int ci = 0; ci < 16; ++ci) {
        const float xv = xp[(size_t)ci << 12];
#pragma unroll
        for (int c = 0; c < 8; ++c) {
            aF[c] = fmaf(xv, P.f_w[c * 64 + cibase + ci], aF[c]);
            aG[c] = fmaf(xv, P.g_w[c * 64 + cibase + ci], aG[c]);
            aH[c] = fmaf(xv, P.h_w[c * 64 + cibase + ci], aH[c]);
        }
    }

    if (q) {
        float* cp = comb[q - 1][pl];
#pragma unroll
        for (int c = 0; c < 8; ++c) { cp[c] = aF[c]; cp[8 + c] = aG[c]; cp[16 + c] = aH[c]; }
    }
    __syncthreads();
    if (q == 0) {
#pragma unroll
        for (int k = 0; k < 3; ++k) {
            const float* cp = comb[k][pl];
#pragma unroll
            for (int c = 0; c < 8; ++c) { aF[c] += cp[c]; aG[c] += cp[8 + c]; aH[c] += cp[16 + c]; }
        }

        const float gm = P.gamma[0];
        float fo[8], go[8], ho[8];
#pragma unroll
        for (int c = 0; c < 8; ++c) {
            float invf = P.f_bw[c] * rsqrtf(P.f_bv[c] + EPSBN);
            fo[c] = ((aF[c] + P.f_b[c]) * invf + (P.f_bb[c] - P.f_bm[c] * invf)) * L2E;
            float invg = P.g_bw[c] * rsqrtf(P.g_bv[c] + EPSBN);
            go[c] = (aG[c] + P.g_b[c]) * invg + (P.g_bb[c] - P.g_bm[c] * invg);
            float invh = P.h_bw[c] * rsqrtf(P.h_bv[c] + EPSBN);
            ho[c] = gm * ((aH[c] + P.h_b[c]) * invh + (P.h_bb[c] - P.h_bm[c] * invh));
        }

        unsigned short fhi[8], flo[8], ghi[8], glo[8];
#pragma unroll
        for (int c = 0; c < 8; ++c) {
            fhi[c] = f2bf(fo[c]);
            flo[c] = f2bf(fo[c] - bf2f(fhi[c]));
            ghi[c] = f2bf(go[c]);
            glo[c] = f2bf(go[c] - bf2f(ghi[c]));
        }
        uint4 fA, fB, gA, gB;
        fA.x = (unsigned)fhi[0] | ((unsigned)fhi[1] << 16);
        fA.y = (unsigned)fhi[2] | ((unsigned)fhi[3] << 16);
        fA.z = (unsigned)fhi[4] | ((unsigned)fhi[5] << 16);
        fA.w = (unsigned)fhi[6] | ((unsigned)fhi[7] << 16);
        fB.x = (unsigned)flo[0] | ((unsigned)flo[1] << 16);
        fB.y = (unsigned)flo[2] | ((unsigned)flo[3] << 16);
        fB.z = (unsigned)flo[4] | ((unsigned)flo[5] << 16);
        fB.w = (unsigned)flo[6] | ((unsigned)flo[7] << 16);
        gA.x = (unsigned)ghi[0] | ((unsigned)ghi[1] << 16);
        gA.y = (unsigned)ghi[2] | ((unsigned)ghi[3] << 16);
        gA.z = (unsigned)ghi[4] | ((unsigned)ghi[5] << 16);
        gA.w = (unsigned)ghi[6] | ((unsigned)ghi[7] << 16);
        gB.x = (unsigned)glo[0] | ((unsigned)glo[1] << 16);
        gB.y = (unsigned)glo[2] | ((unsigned)glo[3] << 16);
        gB.z = (unsigned)glo[4] | ((unsigned)glo[5] << 16);
        gB.w = (unsigned)glo[6] | ((unsigned)glo[7] << 16);

        *(uint4*)(P.fbuf + ((size_t)pix << 4))     = fA;
        *(uint4*)(P.fbuf + ((size_t)pix << 4) + 8) = fB;
        *(uint4*)(P.gbuf + ((size_t)pix << 4))     = gA;
        *(uint4*)(P.gbuf + ((size_t)pix << 4) + 8) = gB;

        float4* hp = (float4*)(P.hbuf + ((size_t)pix << 3));
        hp[0] = make_float4(ho[0], ho[1], ho[2], ho[3]);
        hp[1] = make_float4(ho[4], ho[5], ho[6], ho[7]);
    }
}

// ---------------------------------------------------------------------------
// Pass1 phase: transposed QK, lane-local D. bid -> (mt=bid&127, b=bid>>7).
// Needs 640 B LDS arena.
// ---------------------------------------------------------------------------
__device__ __forceinline__ void pass1_phase(const Params& P, char* smem,
                                            int bid, int tid)
{
    float (*Dp)[32] = (float (*)[32])smem;
    float* Dscale = (float*)(smem + 512);

    const int b = bid >> 7;
    const int mt0 = (bid & 127) << 5;
    const int wv = tid >> 6, l = tid & 63, col = l & 31;
    const int hl8 = (l >> 5) << 3;

    const unsigned short* grow = P.gbuf + (((size_t)(b * 4096 + mt0 + col)) << 4);
    const bf16x8 Ghi = *(const bf16x8*)(grow);
    const bf16x8 Glo = *(const bf16x8*)(grow + 8);

    const f32x16 Z = {0.f, 0.f, 0.f, 0.f, 0.f, 0.f, 0.f, 0.f,
                      0.f, 0.f, 0.f, 0.f, 0.f, 0.f, 0.f, 0.f};
    float Dacc = 0.f;

    const unsigned short* fbase = P.fbuf + (((size_t)(b * 4096 + (wv << 10))) << 4) + hl8;

    __builtin_amdgcn_s_setprio(1);
    for (int nc = 0; nc < 32; ++nc) {
        const bf16x8 Ff = *(const bf16x8*)(fbase + ((size_t)((nc << 5) + col) << 4));
        f32x16 T = __builtin_amdgcn_mfma_f32_32x32x16_bf16(Ff, Ghi, Z, 0, 0, 0);
        T = __builtin_amdgcn_mfma_f32_32x32x16_bf16(Ff, Glo, T, 0, 0, 0);
#pragma unroll
        for (int r = 0; r < 16; ++r)
            Dacc += __builtin_amdgcn_exp2f(T[r]);
    }
    __builtin_amdgcn_s_setprio(0);

    Dacc += __shfl_xor(Dacc, 32);
    if (l < 32) Dp[wv][col] = Dacc;
    __syncthreads();
    if (tid < 32) {
        const float D = Dp[0][tid] + Dp[1][tid] + Dp[2][tid] + Dp[3][tid];
        Dscale[tid] = 1.f / D;
    }
    __syncthreads();
    if (tid < 64) {
        const int ml = tid & 31, c0 = (tid >> 5) << 2;
        const float sc = Dscale[ml];
        const float4 hv = *(const float4*)(P.hbuf + (((size_t)(b * 4096 + mt0 + ml)) << 3) + c0);
        unsigned short* o = P.hT + ((size_t)b << 15) + mt0 + ml;
        o[(size_t)(c0    ) << 12] = f2bf(hv.x * sc);
        o[(size_t)(c0 + 1) << 12] = f2bf(hv.y * sc);
        o[(size_t)(c0 + 2) << 12] = f2bf(hv.z * sc);
        o[(size_t)(c0 + 3) << 12] = f2bf(hv.w * sc);
    }
}

// ---------------------------------------------------------------------------
// Pass2 + post phase: bid -> (nt=bid&127, b=bid>>7). Needs 9,728 B arena.
// ---------------------------------------------------------------------------
__device__ __forceinline__ void pass2_phase(const Params& P, char* smem,
                                            int bid, int tid)
{
    float (*red)[64][4] = (float (*)[64][4])smem;
    float (*os)[8] = (float (*)[8])(smem + 4096);
    unsigned short (*ls)[72] = (unsigned short (*)[72])(smem + 5120);

    const int b = bid >> 7, nt = bid & 127;
    const int wv = tid >> 6, l = tid & 63;
    const int col = l & 31;
    const bool lo = l < 32;
    const int hl8 = lo ? 0 : 8;

    const unsigned short* frow = P.fbuf + (((size_t)(b * 4096 + (nt << 5) + col)) << 4);
    const bf16x8 Fhi = *(const bf16x8*)frow;
    const bf16x8 Flo = *(const bf16x8*)(frow + 8);

    const f32x16 Z = {0.f, 0.f, 0.f, 0.f, 0.f, 0.f, 0.f, 0.f,
                      0.f, 0.f, 0.f, 0.f, 0.f, 0.f, 0.f, 0.f};
    f32x16 Oacc = Z;

    const unsigned short* hbase = P.hT + ((size_t)b << 15) + ((size_t)col << 12) + hl8;
    const bool hvalid = col < 8;

    __builtin_amdgcn_s_setprio(1);
    for (int mci = 0; mci < 32; ++mci) {
        const int mc = (wv << 5) + mci;
        const bf16x8 Gf = *(const bf16x8*)(P.gbuf + (((size_t)(b * 4096 + (mc << 5) + col)) << 4) + hl8);
        f32x16 T = __builtin_amdgcn_mfma_f32_32x32x16_bf16(Gf, Fhi, Z, 0, 0, 0);
        T = __builtin_amdgcn_mfma_f32_32x32x16_bf16(Gf, Flo, T, 0, 0, 0);

        unsigned w[8];
#pragma unroll
        for (int pp = 0; pp < 8; ++pp)
            w[pp] = cvt_pk_bf16(__builtin_amdgcn_exp2f(T[2 * pp]),
                                __builtin_amdgcn_exp2f(T[2 * pp + 1]));

        asm("v_permlane32_swap_b32 %0, %1" : "+v"(w[0]), "+v"(w[2]));
        asm("v_permlane32_swap_b32 %0, %1" : "+v"(w[1]), "+v"(w[3]));
        asm("v_permlane32_swap_b32 %0, %1" : "+v"(w[4]), "+v"(w[6]));
        asm("v_permlane32_swap_b32 %0, %1" : "+v"(w[5]), "+v"(w[7]));

        union { unsigned u[4]; bf16x8 v; } B1, B2;
        B1.u[0] = w[0]; B1.u[1] = w[1]; B1.u[2] = w[2]; B1.u[3] = w[3];
        B2.u[0] = w[4]; B2.u[1] = w[5]; B2.u[2] = w[6]; B2.u[3] = w[7];

        bf16x8 A1 = {0, 0, 0, 0, 0, 0, 0, 0};
        bf16x8 A2 = {0, 0, 0, 0, 0, 0, 0, 0};
        if (hvalid) {
            A1 = *(const bf16x8*)(hbase + (mc << 5));
            A2 = *(const bf16x8*)(hbase + (mc << 5) + 16);
        }
        Oacc = __builtin_amdgcn_mfma_f32_32x32x16_bf16(A1, B1.v, Oacc, 0, 0, 0);
        Oacc = __builtin_amdgcn_mfma_f32_32x32x16_bf16(A2, B2.v, Oacc, 0, 0, 0);
    }
    __builtin_amdgcn_s_setprio(0);

    *(float4*)&red[wv][l][0] = make_float4(Oacc[0], Oacc[1], Oacc[2], Oacc[3]);
    __syncthreads();
    if (tid < 64) {
        const float4 s0 = *(const float4*)&red[0][tid][0];
        const float4 s1 = *(const float4*)&red[1][tid][0];
        const float4 s2 = *(const float4*)&red[2][tid][0];
        const float4 s3 = *(const float4*)&red[3][tid][0];
        *(float4*)&os[tid & 31][(tid >> 5) << 2] =
            make_float4(s0.x + s1.x + s2.x + s3.x,
                        s0.y + s1.y + s2.y + s3.y,
                        s0.z + s1.z + s2.z + s3.z,
                        s0.w + s1.w + s2.w + s3.w);
    }
    __syncthreads();

    {
        const int co = tid & 63, pg = tid >> 6;
        const int p0 = nt << 5;
        const float inv = P.i_bw[co] * rsqrtf(P.i_bv[co] + EPSBN);
        const float bs  = P.i_b[co] * inv + P.i_bb[co] - P.i_bm[co] * inv;
        float iw[8];
#pragma unroll
        for (int c = 0; c < 8; ++c) iw[c] = P.i_w[co * 8 + c] * inv;

        const float* o1p = P.out1 + (((size_t)(b * 64 + co)) << 12) + p0 + pg * 8;
        const float4 r1 = *(const float4*)o1p;
        const float4 r2 = *(const float4*)(o1p + 4);
        const float rv[8] = {r1.x, r1.y, r1.z, r1.w, r2.x, r2.y, r2.z, r2.w};

#pragma unroll
        for (int k = 0; k < 8; ++k) {
            const int pix = pg * 8 + k;
            const float4 oa = *(const float4*)&os[pix][0];
            const float4 ob = *(const float4*)&os[pix][4];
            const float v = oa.x * iw[0] + oa.y * iw[1] + oa.z * iw[2] + oa.w * iw[3]
                          + ob.x * iw[4] + ob.y * iw[5] + ob.z * iw[6] + ob.w * iw[7];
            ls[pix][co] = f2bf(v + bs + rv[k]);
        }
    }
    __syncthreads();
    if (tid < 128) {
        const int pix = tid >> 2, cgi = tid & 3;
        unsigned short* dst = P.out2T + (((size_t)(b * 4096 + (nt << 5) + pix)) << 6) + (cgi << 4);
        *(uint4*)dst       = *(const uint4*)&ls[pix][cgi << 4];
        *(uint4*)(dst + 8) = *(const uint4*)&ls[pix][(cgi << 4) + 8];
    }
}

// ---------------------------------------------------------------------------
// Cooperative fused kernel: 512 blocks x 256 threads, 6 phases.
// ---------------------------------------------------------------------------
__global__ __launch_bounds__(256, 2) void fused_k(Params P)
{
    __shared__ __align__(16) char smem[78688];
    cg::grid_group grid = cg::this_grid();

    const int bid = blockIdx.x;
    const int tid = threadIdx.x;

    prep_phase(P, smem, bid, tid);
    __threadfence(); grid.sync();

    conv_phase(P.xT, P.wt1, P.out1, smem, bid, tid);
    __threadfence(); grid.sync();

    if (bid < 256) proj_phase(P, smem, bid, tid);
    __threadfence(); grid.sync();

    pass1_phase(P, smem, bid, tid);
    __threadfence(); grid.sync();

    pass2_phase(P, smem, bid, tid);
    __threadfence(); grid.sync();

    conv_phase(P.out2T, P.wt2, P.out, smem, bid, tid);
}

// ---------------------------------------------------------------------------
// Fallback wrappers (bit-identical phase code, linear grids == R16 mapping).
// ---------------------------------------------------------------------------
__global__ __launch_bounds__(256) void prep_w(Params P) {
    __shared__ __align__(16) char smem[9216];
    prep_phase(P, smem, blockIdx.x, threadIdx.x);
}
__global__ __launch_bounds__(256) void conv_w(Params P, int which) {
    __shared__ __align__(16) char smem[78688];
    if (which == 0)
        conv_phase(P.xT, P.wt1, P.out1, smem, blockIdx.x, threadIdx.x);
    else
        conv_phase(P.out2T, P.wt2, P.out, smem, blockIdx.x, threadIdx.x);
}
__global__ __launch_bounds__(256) void proj_w(Params P) {
    __shared__ __align__(16) char smem[19456];
    proj_phase(P, smem, blockIdx.x, threadIdx.x);
}
__global__ __launch_bounds__(256) void pass1_w(Params P) {
    __shared__ __align__(16) char smem[640];
    pass1_phase(P, smem, blockIdx.x, threadIdx.x);
}
__global__ __launch_bounds__(256) void pass2_w(Params P) {
    __shared__ __align__(16) char smem[9728];
    pass2_phase(P, smem, blockIdx.x, threadIdx.x);
}

// ---------------------------------------------------------------------------
extern "C" void kernel_launch(void* const* d_in, const int* in_sizes, int n_in,
                              void* d_out, int out_size, void* d_ws, size_t ws_size,
                              hipStream_t stream) {
    float* ws = (float*)d_ws;

    Params P;
    P.x       = (const float*)d_in[0];
    P.w1      = (const float*)d_in[1];
    P.w2      = (const float*)d_in[2];
    P.f_w  = (const float*)d_in[3];
    P.f_b  = (const float*)d_in[4];
    P.f_bw = (const float*)d_in[5];
    P.f_bb = (const float*)d_in[6];
    P.f_bm = (const float*)d_in[7];
    P.f_bv = (const float*)d_in[8];
    P.g_w  = (const float*)d_in[9];
    P.g_b  = (const float*)d_in[10];
    P.g_bw = (const float*)d_in[11];
    P.g_bb = (const float*)d_in[12];
    P.g_bm = (const float*)d_in[13];
    P.g_bv = (const float*)d_in[14];
    P.gamma = (const float*)d_in[15];
    P.h_w  = (const float*)d_in[16];
    P.h_b  = (const float*)d_in[17];
    P.h_bw = (const float*)d_in[18];
    P.h_bb = (const float*)d_in[19];
    P.h_bm = (const float*)d_in[20];
    P.h_bv = (const float*)d_in[21];
    P.i_w  = (const float*)d_in[22];
    P.i_b  = (const float*)d_in[23];
    P.i_bw = (const float*)d_in[24];
    P.i_bb = (const float*)d_in[25];
    P.i_bm = (const float*)d_in[26];
    P.i_bv = (const float*)d_in[27];

    P.out1  = ws;                                        // 1,048,576 f
    P.xT    = (unsigned short*)(ws + 1048576);           //   524,288 f
    P.fbuf  = (unsigned short*)(ws + 1572864);           //   131,072 f
    P.gbuf  = (unsigned short*)(ws + 1703936);           //   131,072 f
    P.hbuf  = ws + 1835008;                              //   131,072 f
    P.hT    = (unsigned short*)(ws + 1966080);           //    65,536 f
    P.wt1   = (unsigned short*)(ws + 2031616);           //    18,432 f
    P.wt2   = (unsigned short*)(ws + 2050048);           //    18,432 f
    P.out2T = (unsigned short*)(ws + 2068480);           //   524,288 f
    P.out   = (float*)d_out;

    void* args[] = { &P };
    hipError_t err = hipLaunchCooperativeKernel((const void*)fused_k,
                                                dim3(512), dim3(256),
                                                args, 0, stream);
    if (err != hipSuccess) {
        // fallback: same phases as separate kernels (R16-identical results)
        prep_w<<<292, 256, 0, stream>>>(P);
        conv_w<<<512, 256, 0, stream>>>(P, 0);
        proj_w<<<256, 256, 0, stream>>>(P);
        pass1_w<<<512, 256, 0, stream>>>(P);
        pass2_w<<<512, 256, 0, stream>>>(P);
        conv_w<<<512, 256, 0, stream>>>(P, 1);
    }
}

// Round 19
// 76.032 us; speedup vs baseline: 7.9653x; 7.9653x over previous
//
#include <hip/hip_runtime.h>

#define EPSBN 1e-5f
#define L2E 1.44269504088896340736f

typedef __attribute__((ext_vector_type(4)))  float f32x4;
typedef __attribute__((ext_vector_type(16))) float f32x16;
typedef __attribute__((ext_vector_type(8)))  short bf16x8;

__device__ __forceinline__ unsigned short f2bf(float f) {
    unsigned u = __float_as_uint(f);
    u = (u + 0x7FFFu + ((u >> 16) & 1u)) >> 16;
    return (unsigned short)u;
}
__device__ __forceinline__ float bf2f(unsigned short h) {
    return __uint_as_float((unsigned)h << 16);
}
__device__ __forceinline__ unsigned cvt_pk_bf16(float lo, float hi) {
    unsigned r;
    asm("v_cvt_pk_bf16_f32 %0, %1, %2" : "=v"(r) : "v"(lo), "v"(hi));
    return r;
}

// ---------------------------------------------------------------------------
// K0 prep: blocks 0..255: x (fp32 channel-major) -> xT bf16 pixel-major
//          blocks 256..291: conv1_w/conv2_w -> wt1/wt2 bf16 [t][co][ci]
// ---------------------------------------------------------------------------
__global__ __launch_bounds__(256) void prep_k(
    const float* __restrict__ x, const float* __restrict__ w1,
    const float* __restrict__ w2,
    unsigned short* __restrict__ xT, unsigned short* __restrict__ wt1,
    unsigned short* __restrict__ wt2)
{
    const int tid = threadIdx.x;
    if (blockIdx.x < 256) {
        __shared__ unsigned short tls[64][72];
        const int b = blockIdx.x >> 6, p0 = (blockIdx.x & 63) << 6;
        const int ci = tid >> 2, pq = tid & 3;
        const float* src = x + (((size_t)(b * 64 + ci)) << 12) + p0 + pq * 16;
#pragma unroll
        for (int j = 0; j < 4; ++j) {
            const float4 v = *(const float4*)(src + j * 4);
            const int pl = pq * 16 + j * 4;
            tls[pl][ci]     = f2bf(v.x);
            tls[pl + 1][ci] = f2bf(v.y);
            tls[pl + 2][ci] = f2bf(v.z);
            tls[pl + 3][ci] = f2bf(v.w);
        }
        __syncthreads();
        const int pix = tid >> 2, cg = tid & 3;
        const uint4 a  = *(const uint4*)&tls[pix][cg << 4];
        const uint4 b2 = *(const uint4*)&tls[pix][(cg << 4) + 8];
        unsigned short* dst = xT + (((size_t)((b << 12) + p0 + pix)) << 6) + (cg << 4);
        *(uint4*)dst       = a;
        *(uint4*)(dst + 8) = b2;
    } else {
        const int e0 = (blockIdx.x - 256) * 2048 + tid * 8;
#pragma unroll
        for (int j = 0; j < 8; ++j) {
            const int e = e0 + j;
            const int which = e >= 36864;
            const int je = which ? e - 36864 : e;
            const int t_ = je >> 12, co = (je >> 6) & 63, ci = je & 63;
            const float val = (which ? w2 : w1)[(co * 64 + ci) * 9 + t_];
            (which ? wt2 : wt1)[je] = f2bf(val);
        }
    }
}

// ---------------------------------------------------------------------------
// K1/K5: 3x3 conv via bf16 MFMA. Input = pixel-major bf16 xT[b][pix][ci].
// Weights staged in LDS. Block = 1 image row x 32 co; grid (64, 2, B).
// ---------------------------------------------------------------------------
__global__ __launch_bounds__(256) void conv3x3_k(
    const unsigned short* __restrict__ xT, const unsigned short* __restrict__ wt,
    float* __restrict__ y)
{
    __shared__ unsigned short xs[3][66][72];
    __shared__ unsigned short ws[9][32][72];
    __shared__ float          ls[32][68];

    const int b  = blockIdx.z;
    const int cg = blockIdx.y;
    const int r0 = blockIdx.x;
    const int tid = threadIdx.x;

    // stage x rows r0-1..r0+1: 16B vector loads, 8-group-aligned ci swizzle
    for (int u = tid; u < 1536; u += 256) {
        const int kh = u >> 9, rem = u & 511;
        const int p = 1 + (rem >> 3), cig = rem & 7;
        const int gr = r0 + kh - 1;
        uint4 v = make_uint4(0u, 0u, 0u, 0u);
        if ((unsigned)gr < 64u)
            v = *(const uint4*)(xT + (((size_t)((b << 12) + (gr << 6) + (p - 1))) << 6) + (cig << 3));
        const int s = (p >> 3) & 7;
        *(uint4*)&xs[kh][p][(cig ^ s) << 3] = v;
    }
    if (tid < 48) {   // zero halo columns p=0, p=65 (swz=0 for both)
        const int kh = tid >> 4, pp = (tid & 8) ? 65 : 0, cig = tid & 7;
        *(uint4*)&xs[kh][pp][cig << 3] = make_uint4(0u, 0u, 0u, 0u);
    }
    // stage weights ws[t][co][ci]
    for (int u = tid; u < 2304; u += 256) {
        const int t_ = u >> 8, rem = u & 255;
        const int co = rem >> 3, cig = rem & 7;
        const uint4 v = *(const uint4*)(wt + (((t_ * 64) + (cg << 5) + co) << 6) + (cig << 3));
        *(uint4*)&ws[t_][co][cig << 3] = v;
    }
    __syncthreads();

    const int lane = tid & 63, grp = tid >> 6;
    const int lr = lane & 15, lk = lane >> 4;
    const int pixbase = (grp << 4) + lr;

    f32x4 acc0 = {0.f, 0.f, 0.f, 0.f};
    f32x4 acc1 = {0.f, 0.f, 0.f, 0.f};

#pragma unroll
    for (int t = 0; t < 9; ++t) {
        const int kh = t / 3, kw = t % 3;
        const int p  = pixbase + kw;
        const int sw = ((p >> 3) & 7) << 3;
#pragma unroll
        for (int ch = 0; ch < 2; ++ch) {
            const int cio = (ch << 5) + (lk << 3);
            const bf16x8 a  = *(const bf16x8*)&xs[kh][p][cio ^ sw];
            const bf16x8 b0 = *(const bf16x8*)&ws[t][lr][cio];
            const bf16x8 b1 = *(const bf16x8*)&ws[t][16 + lr][cio];
            acc0 = __builtin_amdgcn_mfma_f32_16x16x32_bf16(a, b0, acc0, 0, 0, 0);
            acc1 = __builtin_amdgcn_mfma_f32_16x16x32_bf16(a, b1, acc1, 0, 0, 0);
        }
    }

#pragma unroll
    for (int j = 0; j < 4; ++j) {
        const int pix = (grp << 4) + (lk << 2) + j;
        ls[lr][pix]      = acc0[j];
        ls[lr + 16][pix] = acc1[j];
    }
    __syncthreads();

    const int co_l = tid >> 3, pq = (tid & 7) << 3;
    float* yp = y + (((size_t)((b << 6) + (cg << 5) + co_l)) << 12) + (r0 << 6) + pq;
    *(float4*)yp       = *(const float4*)&ls[co_l][pq];
    *(float4*)(yp + 4) = *(const float4*)&ls[co_l][pq + 4];
}

// ---------------------------------------------------------------------------
// K2 proj: f/g/h 1x1-conv + bias + BN (+gamma). 4 threads/pixel (16 ci each),
// LDS combine. f,g -> bf16 hi/lo [B*N][16] (f pre-scaled by L2E); h -> f32.
// grid 256, block 256 (64 pixels/block).
// ---------------------------------------------------------------------------
__global__ __launch_bounds__(256) void proj_k(
    const float* __restrict__ out1,
    const float* __restrict__ f_w, const float* __restrict__ f_b,
    const float* __restrict__ f_bw, const float* __restrict__ f_bb,
    const float* __restrict__ f_bm, const float* __restrict__ f_bv,
    const float* __restrict__ g_w, const float* __restrict__ g_b,
    const float* __restrict__ g_bw, const float* __restrict__ g_bb,
    const float* __restrict__ g_bm, const float* __restrict__ g_bv,
    const float* __restrict__ h_w, const float* __restrict__ h_b,
    const float* __restrict__ h_bw, const float* __restrict__ h_bb,
    const float* __restrict__ h_bm, const float* __restrict__ h_bv,
    const float* __restrict__ gamma,
    unsigned short* __restrict__ fb, unsigned short* __restrict__ gb,
    float* __restrict__ hb)
{
    __shared__ float comb[3][64][25];

    const int pl = threadIdx.x >> 2, q = threadIdx.x & 3;
    const int pix = blockIdx.x * 64 + pl;
    const int b = pix >> 12, p = pix & 4095;
    const int cibase = q << 4;

    const float* xp = out1 + ((size_t)b << 18) + ((size_t)cibase << 12) + p;

    float aF[8], aG[8], aH[8];
#pragma unroll
    for (int c = 0; c < 8; ++c) { aF[c] = 0.f; aG[c] = 0.f; aH[c] = 0.f; }

#pragma unroll
    for (int ci = 0; ci < 16; ++ci) {
        const float xv = xp[(size_t)ci << 12];
#pragma unroll
        for (int c = 0; c < 8; ++c) {
            aF[c] = fmaf(xv, f_w[c * 64 + cibase + ci], aF[c]);
            aG[c] = fmaf(xv, g_w[c * 64 + cibase + ci], aG[c]);
            aH[c] = fmaf(xv, h_w[c * 64 + cibase + ci], aH[c]);
        }
    }

    if (q) {
        float* cp = comb[q - 1][pl];
#pragma unroll
        for (int c = 0; c < 8; ++c) { cp[c] = aF[c]; cp[8 + c] = aG[c]; cp[16 + c] = aH[c]; }
    }
    __syncthreads();
    if (q == 0) {
#pragma unroll
        for (int k = 0; k < 3; ++k) {
            const float* cp = comb[k][pl];
#pragma unroll
            for (int c = 0; c < 8; ++c) { aF[c] += cp[c]; aG[c] += cp[8 + c]; aH[c] += cp[16 + c]; }
        }

        const float gm = gamma[0];
        float fo[8], go[8], ho[8];
#pragma unroll
        for (int c = 0; c < 8; ++c) {
            float invf = f_bw[c] * rsqrtf(f_bv[c] + EPSBN);
            fo[c] = ((aF[c] + f_b[c]) * invf + (f_bb[c] - f_bm[c] * invf)) * L2E;
            float invg = g_bw[c] * rsqrtf(g_bv[c] + EPSBN);
            go[c] = (aG[c] + g_b[c]) * invg + (g_bb[c] - g_bm[c] * invg);
            float invh = h_bw[c] * rsqrtf(h_bv[c] + EPSBN);
            ho[c] = gm * ((aH[c] + h_b[c]) * invh + (h_bb[c] - h_bm[c] * invh));
        }

        unsigned short fhi[8], flo[8], ghi[8], glo[8];
#pragma unroll
        for (int c = 0; c < 8; ++c) {
            fhi[c] = f2bf(fo[c]);
            flo[c] = f2bf(fo[c] - bf2f(fhi[c]));
            ghi[c] = f2bf(go[c]);
            glo[c] = f2bf(go[c] - bf2f(ghi[c]));
        }
        uint4 fA, fB, gA, gB;
        fA.x = (unsigned)fhi[0] | ((unsigned)fhi[1] << 16);
        fA.y = (unsigned)fhi[2] | ((unsigned)fhi[3] << 16);
        fA.z = (unsigned)fhi[4] | ((unsigned)fhi[5] << 16);
        fA.w = (unsigned)fhi[6] | ((unsigned)fhi[7] << 16);
        fB.x = (unsigned)flo[0] | ((unsigned)flo[1] << 16);
        fB.y = (unsigned)flo[2] | ((unsigned)flo[3] << 16);
        fB.z = (unsigned)flo[4] | ((unsigned)flo[5] << 16);
        fB.w = (unsigned)flo[6] | ((unsigned)flo[7] << 16);
        gA.x = (unsigned)ghi[0] | ((unsigned)ghi[1] << 16);
        gA.y = (unsigned)ghi[2] | ((unsigned)ghi[3] << 16);
        gA.z = (unsigned)ghi[4] | ((unsigned)ghi[5] << 16);
        gA.w = (unsigned)ghi[6] | ((unsigned)ghi[7] << 16);
        gB.x = (unsigned)glo[0] | ((unsigned)glo[1] << 16);
        gB.y = (unsigned)glo[2] | ((unsigned)glo[3] << 16);
        gB.z = (unsigned)glo[4] | ((unsigned)glo[5] << 16);
        gB.w = (unsigned)glo[6] | ((unsigned)glo[7] << 16);

        *(uint4*)(fb + ((size_t)pix << 4))     = fA;
        *(uint4*)(fb + ((size_t)pix << 4) + 8) = fB;
        *(uint4*)(gb + ((size_t)pix << 4))     = gA;
        *(uint4*)(gb + ((size_t)pix << 4) + 8) = gB;

        float4* hp = (float4*)(hb + ((size_t)pix << 3));
        hp[0] = make_float4(ho[0], ho[1], ho[2], ho[3]);
        hp[1] = make_float4(ho[4], ho[5], ho[6], ho[7]);
    }
}

// ---------------------------------------------------------------------------
// K3 pass1 (transposed QK, lane-local D): block = one 32-m tile; 4 waves
// split n (1024 each). + s_setprio around hot loop.
// Writes hT = bf16(h/D). grid (128, B), block 256.
// ---------------------------------------------------------------------------
__global__ __launch_bounds__(256) void pass1_k(
    const unsigned short* __restrict__ fb, const unsigned short* __restrict__ gb,
    const float* __restrict__ hb, unsigned short* __restrict__ hT)
{
    __shared__ float Dp[4][32];
    __shared__ float Dscale[32];

    const int b = blockIdx.y;
    const int mt0 = blockIdx.x << 5;
    const int tid = threadIdx.x;
    const int wv = tid >> 6, l = tid & 63, col = l & 31;
    const int hl8 = (l >> 5) << 3;          // 0: hi half, 8: lo half

    const unsigned short* grow = gb + (((size_t)(b * 4096 + mt0 + col)) << 4);
    const bf16x8 Ghi = *(const bf16x8*)(grow);
    const bf16x8 Glo = *(const bf16x8*)(grow + 8);

    const f32x16 Z = {0.f, 0.f, 0.f, 0.f, 0.f, 0.f, 0.f, 0.f,
                      0.f, 0.f, 0.f, 0.f, 0.f, 0.f, 0.f, 0.f};
    float Dacc = 0.f;

    const unsigned short* fbase = fb + (((size_t)(b * 4096 + (wv << 10))) << 4) + hl8;

    __builtin_amdgcn_s_setprio(1);
    for (int nc = 0; nc < 32; ++nc) {
        const bf16x8 Ff = *(const bf16x8*)(fbase + ((size_t)((nc << 5) + col) << 4));
        f32x16 T = __builtin_amdgcn_mfma_f32_32x32x16_bf16(Ff, Ghi, Z, 0, 0, 0);
        T = __builtin_amdgcn_mfma_f32_32x32x16_bf16(Ff, Glo, T, 0, 0, 0);
#pragma unroll
        for (int r = 0; r < 16; ++r)
            Dacc += __builtin_amdgcn_exp2f(T[r]);
    }
    __builtin_amdgcn_s_setprio(0);

    Dacc += __shfl_xor(Dacc, 32);   // combine row-quarters (same m, two halves)
    if (l < 32) Dp[wv][col] = Dacc;
    __syncthreads();
    if (tid < 32) {
        const float D = Dp[0][tid] + Dp[1][tid] + Dp[2][tid] + Dp[3][tid];
        Dscale[tid] = 1.f / D;
    }
    __syncthreads();
    if (tid < 64) {
        const int ml = tid & 31, c0 = (tid >> 5) << 2;
        const float sc = Dscale[ml];
        const float4 hv = *(const float4*)(hb + (((size_t)(b * 4096 + mt0 + ml)) << 3) + c0);
        unsigned short* o = hT + ((size_t)b << 15) + mt0 + ml;
        o[(size_t)(c0    ) << 12] = f2bf(hv.x * sc);
        o[(size_t)(c0 + 1) << 12] = f2bf(hv.y * sc);
        o[(size_t)(c0 + 2) << 12] = f2bf(hv.z * sc);
        o[(size_t)(c0 + 3) << 12] = f2bf(hv.w * sc);
    }
}

// ---------------------------------------------------------------------------
// K4 pass2 + post (fused): block = one 32-n tile; 4 waves split m (1024 each).
// Exact hi/lo QK; P -> bf16 via cvt_pk + v_permlane32_swap; O^T += mfma(hT,P).
// LDS-combine O, then i-conv + BN + residual; emits out2T bf16 pixel-major.
// grid (128, B), block 256. + s_setprio around hot loop.
// ---------------------------------------------------------------------------
__global__ __launch_bounds__(256) void pass2_k(
    const unsigned short* __restrict__ fb, const unsigned short* __restrict__ gb,
    const unsigned short* __restrict__ hT,
    const float* __restrict__ out1,
    const float* __restrict__ i_w, const float* __restrict__ i_b,
    const float* __restrict__ i_bw, const float* __restrict__ i_bb,
    const float* __restrict__ i_bm, const float* __restrict__ i_bv,
    unsigned short* __restrict__ out2T)
{
    __shared__ float red[4][64][4];
    __shared__ float os[32][8];
    __shared__ unsigned short ls[32][72];

    const int b = blockIdx.y, nt = blockIdx.x;
    const int tid = threadIdx.x, wv = tid >> 6, l = tid & 63;
    const int col = l & 31;
    const bool lo = l < 32;
    const int hl8 = lo ? 0 : 8;

    const unsigned short* frow = fb + (((size_t)(b * 4096 + (nt << 5) + col)) << 4);
    const bf16x8 Fhi = *(const bf16x8*)frow;
    const bf16x8 Flo = *(const bf16x8*)(frow + 8);

    const f32x16 Z = {0.f, 0.f, 0.f, 0.f, 0.f, 0.f, 0.f, 0.f,
                      0.f, 0.f, 0.f, 0.f, 0.f, 0.f, 0.f, 0.f};
    f32x16 Oacc = Z;

    const unsigned short* hbase = hT + ((size_t)b << 15) + ((size_t)col << 12) + hl8;
    const bool hvalid = col < 8;

    __builtin_amdgcn_s_setprio(1);
    for (int mci = 0; mci < 32; ++mci) {
        const int mc = (wv << 5) + mci;
        const bf16x8 Gf = *(const bf16x8*)(gb + (((size_t)(b * 4096 + (mc << 5) + col)) << 4) + hl8);
        f32x16 T = __builtin_amdgcn_mfma_f32_32x32x16_bf16(Gf, Fhi, Z, 0, 0, 0);
        T = __builtin_amdgcn_mfma_f32_32x32x16_bf16(Gf, Flo, T, 0, 0, 0);

        unsigned w[8];
#pragma unroll
        for (int pp = 0; pp < 8; ++pp)
            w[pp] = cvt_pk_bf16(__builtin_amdgcn_exp2f(T[2 * pp]),
                                __builtin_amdgcn_exp2f(T[2 * pp + 1]));

        // v_permlane32_swap_b32 a,b: a' = {a.lo, b.lo}, b' = {a.hi, b.hi}
        asm("v_permlane32_swap_b32 %0, %1" : "+v"(w[0]), "+v"(w[2]));
        asm("v_permlane32_swap_b32 %0, %1" : "+v"(w[1]), "+v"(w[3]));
        asm("v_permlane32_swap_b32 %0, %1" : "+v"(w[4]), "+v"(w[6]));
        asm("v_permlane32_swap_b32 %0, %1" : "+v"(w[5]), "+v"(w[7]));

        union { unsigned u[4]; bf16x8 v; } B1, B2;
        B1.u[0] = w[0]; B1.u[1] = w[1]; B1.u[2] = w[2]; B1.u[3] = w[3];
        B2.u[0] = w[4]; B2.u[1] = w[5]; B2.u[2] = w[6]; B2.u[3] = w[7];

        bf16x8 A1 = {0, 0, 0, 0, 0, 0, 0, 0};
        bf16x8 A2 = {0, 0, 0, 0, 0, 0, 0, 0};
        if (hvalid) {
            A1 = *(const bf16x8*)(hbase + (mc << 5));
            A2 = *(const bf16x8*)(hbase + (mc << 5) + 16);
        }
        Oacc = __builtin_amdgcn_mfma_f32_32x32x16_bf16(A1, B1.v, Oacc, 0, 0, 0);
        Oacc = __builtin_amdgcn_mfma_f32_32x32x16_bf16(A2, B2.v, Oacc, 0, 0, 0);
    }
    __builtin_amdgcn_s_setprio(0);

    *(float4*)&red[wv][l][0] = make_float4(Oacc[0], Oacc[1], Oacc[2], Oacc[3]);
    __syncthreads();
    if (tid < 64) {
        const float4 s0 = *(const float4*)&red[0][tid][0];
        const float4 s1 = *(const float4*)&red[1][tid][0];
        const float4 s2 = *(const float4*)&red[2][tid][0];
        const float4 s3 = *(const float4*)&red[3][tid][0];
        *(float4*)&os[tid & 31][(tid >> 5) << 2] =
            make_float4(s0.x + s1.x + s2.x + s3.x,
                        s0.y + s1.y + s2.y + s3.y,
                        s0.z + s1.z + s2.z + s3.z,
                        s0.w + s1.w + s2.w + s3.w);
    }
    __syncthreads();

    // post: i-conv + BN + residual; co = tid&63, 8 pixels per thread.
    {
        const int co = tid & 63, pg = tid >> 6;
        const int p0 = nt << 5;
        const float inv = i_bw[co] * rsqrtf(i_bv[co] + EPSBN);
        const float bs  = i_b[co] * inv + i_bb[co] - i_bm[co] * inv;
        float iw[8];
#pragma unroll
        for (int c = 0; c < 8; ++c) iw[c] = i_w[co * 8 + c] * inv;

        const float* o1p = out1 + (((size_t)(b * 64 + co)) << 12) + p0 + pg * 8;
        const float4 r1 = *(const float4*)o1p;
        const float4 r2 = *(const float4*)(o1p + 4);
        const float rv[8] = {r1.x, r1.y, r1.z, r1.w, r2.x, r2.y, r2.z, r2.w};

#pragma unroll
        for (int k = 0; k < 8; ++k) {
            const int pix = pg * 8 + k;
            const float4 oa = *(const float4*)&os[pix][0];
            const float4 ob = *(const float4*)&os[pix][4];
            const float v = oa.x * iw[0] + oa.y * iw[1] + oa.z * iw[2] + oa.w * iw[3]
                          + ob.x * iw[4] + ob.y * iw[5] + ob.z * iw[6] + ob.w * iw[7];
            ls[pix][co] = f2bf(v + bs + rv[k]);
        }
    }
    __syncthreads();
    if (tid < 128) {
        const int pix = tid >> 2, cgi = tid & 3;
        unsigned short* dst = out2T + (((size_t)(b * 4096 + (nt << 5) + pix)) << 6) + (cgi << 4);
        *(uint4*)dst       = *(const uint4*)&ls[pix][cgi << 4];
        *(uint4*)(dst + 8) = *(const uint4*)&ls[pix][(cgi << 4) + 8];
    }
}

// ---------------------------------------------------------------------------
extern "C" void kernel_launch(void* const* d_in, const int* in_sizes, int n_in,
                              void* d_out, int out_size, void* d_ws, size_t ws_size,
                              hipStream_t stream) {
    const float* x       = (const float*)d_in[0];
    const float* conv1_w = (const float*)d_in[1];
    const float* conv2_w = (const float*)d_in[2];
    const float* f_w  = (const float*)d_in[3];
    const float* f_b  = (const float*)d_in[4];
    const float* f_bw = (const float*)d_in[5];
    const float* f_bb = (const float*)d_in[6];
    const float* f_bm = (const float*)d_in[7];
    const float* f_bv = (const float*)d_in[8];
    const float* g_w  = (const float*)d_in[9];
    const float* g_b  = (const float*)d_in[10];
    const float* g_bw = (const float*)d_in[11];
    const float* g_bb = (const float*)d_in[12];
    const float* g_bm = (const float*)d_in[13];
    const float* g_bv = (const float*)d_in[14];
    const float* gamma = (const float*)d_in[15];
    const float* h_w  = (const float*)d_in[16];
    const float* h_b  = (const float*)d_in[17];
    const float* h_bw = (const float*)d_in[18];
    const float* h_bb = (const float*)d_in[19];
    const float* h_bm = (const float*)d_in[20];
    const float* h_bv = (const float*)d_in[21];
    const float* i_w  = (const float*)d_in[22];
    const float* i_b  = (const float*)d_in[23];
    const float* i_bw = (const float*)d_in[24];
    const float* i_bb = (const float*)d_in[25];
    const float* i_bm = (const float*)d_in[26];
    const float* i_bv = (const float*)d_in[27];

    float* ws = (float*)d_ws;
    float* out1 = ws;                                          // 1,048,576 f
    unsigned short* xT    = (unsigned short*)(ws + 1048576);   //   524,288 f
    unsigned short* fbuf  = (unsigned short*)(ws + 1572864);   //   131,072 f
    unsigned short* gbuf  = (unsigned short*)(ws + 1703936);   //   131,072 f
    float* hbuf = ws + 1835008;                                //   131,072 f
    unsigned short* hT    = (unsigned short*)(ws + 1966080);   //    65,536 f
    unsigned short* wt1   = (unsigned short*)(ws + 2031616);   //    18,432 f
    unsigned short* wt2   = (unsigned short*)(ws + 2050048);   //    18,432 f
    unsigned short* out2T = (unsigned short*)(ws + 2068480);   //   524,288 f

    // K0: x -> xT (bf16 pixel-major); weights -> wt1/wt2 (bf16 [t][co][ci])
    prep_k<<<292, 256, 0, stream>>>(x, conv1_w, conv2_w, xT, wt1, wt2);

    // K1: conv1 (MFMA, LDS weights) -> out1 (fp32 channel-major)
    conv3x3_k<<<dim3(64, 2, 4), 256, 0, stream>>>(xT, wt1, out1);

    // K2: projections -> f,g bf16 hi/lo (f has L2E), h f32
    proj_k<<<256, 256, 0, stream>>>(out1,
        f_w, f_b, f_bw, f_bb, f_bm, f_bv,
        g_w, g_b, g_bw, g_bb, g_bm, g_bv,
        h_w, h_b, h_bw, h_bb, h_bm, h_bv,
        gamma, fbuf, gbuf, hbuf);

    // K3: pass1 MFMA (transposed, lane-local D) -> hT = bf16(h / D)
    pass1_k<<<dim3(128, 4), 256, 0, stream>>>(fbuf, gbuf, hbuf, hT);

    // K4: pass2 MFMA + i-conv + BN + residual -> out2T (bf16 pixel-major)
    pass2_k<<<dim3(128, 4), 256, 0, stream>>>(fbuf, gbuf, hT, out1,
        i_w, i_b, i_bw, i_bb, i_bm, i_bv, out2T);

    // K5: conv2 (MFMA, LDS weights) -> d_out
    conv3x3_k<<<dim3(64, 2, 4), 256, 0, stream>>>(out2T, wt2, (float*)d_out);
}